// Round 4
// baseline (15534.499 us; speedup 1.0000x reference)
//
#include <hip/hip_runtime.h>
#include <cmath>

// Problem dims (fixed by reference)
#define B_   128
#define T_   500
#define MEL_ 80
#define RED_ 2
#define D_   256   // decoder dim
#define E_   128   // encoder/prenet-out dim
#define PRE_ 256   // prenet hidden
#define L_   256   // encoder length
#define TPB  1024
#define ENC_C 256  // ushorts per enc row (512B exactly; XOR-swizzled 16B chunks)
#define PTT  10    // timesteps per pre-pass block (500 % 10 == 0)

__device__ __forceinline__ float sigmoidf_(float x) { return 1.f / (1.f + expf(-x)); }
__device__ __forceinline__ float bflo(unsigned u) { return __uint_as_float(u << 16); }
__device__ __forceinline__ float bfhi(unsigned u) { return __uint_as_float(u & 0xFFFF0000u); }
__device__ __forceinline__ float bfval(ushort v) { return __uint_as_float(((unsigned)v) << 16); }
__device__ __forceinline__ ushort f2bf(float f) {
    unsigned u = __float_as_uint(f);
    return (ushort)((u + 0x7FFFu + ((u >> 16) & 1u)) >> 16);
}

// accumulate 8 bf16 (one uint4) against 8 fp32
__device__ __forceinline__ float acc8(uint4 u, const float* vv, float s) {
    s = fmaf(bflo(u.x), vv[0], s);
    s = fmaf(bfhi(u.x), vv[1], s);
    s = fmaf(bflo(u.y), vv[2], s);
    s = fmaf(bfhi(u.y), vv[3], s);
    s = fmaf(bflo(u.z), vv[4], s);
    s = fmaf(bfhi(u.z), vv[5], s);
    s = fmaf(bflo(u.w), vv[6], s);
    s = fmaf(bfhi(u.w), vv[7], s);
    return s;
}

// Wave-group-sequential packed bf16 weights: tasks grouped 64 per wave;
// group g stores all CH chunks contiguously: uint4 index (g*CH + c)*64 + lane.
// Every wave load is 1KB fully contiguous; per-wave stream is one sequential
// burst. 4 accumulators + <=8 loads in flight (unroll 2): no spill at 64 VGPR.
template<int CH>
__device__ __forceinline__ float dotpk(const ushort* __restrict__ wp, int t, const float* v) {
    const uint4* w = reinterpret_cast<const uint4*>(wp) + (t >> 6) * (CH * 64) + (t & 63);
    float s0 = 0.f, s1 = 0.f, s2 = 0.f, s3 = 0.f;
#pragma unroll 2
    for (int c = 0; c < (CH & ~3); c += 4) {
        uint4 u0 = w[(c + 0) * 64];
        uint4 u1 = w[(c + 1) * 64];
        uint4 u2 = w[(c + 2) * 64];
        uint4 u3 = w[(c + 3) * 64];
        s0 = acc8(u0, v + (c + 0) * 8, s0);
        s1 = acc8(u1, v + (c + 1) * 8, s1);
        s2 = acc8(u2, v + (c + 2) * 8, s2);
        s3 = acc8(u3, v + (c + 3) * 8, s3);
    }
    if (CH & 2) {
        constexpr int c0 = CH & ~3;
        uint4 u0 = w[(c0 + 0) * 64];
        uint4 u1 = w[(c0 + 1) * 64];
        s0 = acc8(u0, v + (c0 + 0) * 8, s0);
        s1 = acc8(u1, v + (c0 + 1) * 8, s1);
    }
    return (s0 + s1) + (s2 + s3);
}

// fp32 source -> bf16 wave-group-sequential packed layout.
// dst elem i: i4=i>>3, e=i&7; lane=i4&63; q=i4>>6; c=q%CH; g=q/CH; t=g*64+lane;
// src index = (t/dA)*mA + (t%dA)*mB + c*8 + e
__global__ void pack_bf16_kernel(const float* __restrict__ src,
                                 ushort* __restrict__ dst,
                                 int NT, int CH, int dA, int mA, int mB) {
    int i = blockIdx.x * blockDim.x + threadIdx.x;
    int n = NT * CH * 8;
    if (i >= n) return;
    int i4 = i >> 3, e = i & 7;
    int lane = i4 & 63;
    int q = i4 >> 6;
    int c = q % CH;
    int g = q / CH;
    int t = g * 64 + lane;
    dst[i] = f2bf(src[(t / dA) * mA + (t % dA) * mB + c * 8 + e]);
}

// -------- Pre-pass: prenet + attention-GRU input gates for ALL (b,t) --------
// gi[b,t,r] = attn_wih[r,:] @ relu(pre_w2 @ relu(pre_w1 @ frame + b1) + b2) + attn_bih[r]
// State-independent -> hoisted out of the serial loop. fp32 math, bf16 store.
__global__ __launch_bounds__(256) void prenet_gi_kernel(
    const float* __restrict__ dec_input,
    const float* __restrict__ pre_w1, const float* __restrict__ pre_b1,
    const float* __restrict__ pre_w2, const float* __restrict__ pre_b2,
    const float* __restrict__ attn_wih, const float* __restrict__ attn_bih,
    ushort* __restrict__ gi_out,   // chunk-local [nb, T, 3*D] bf16
    int b0)
{
    const int blk = blockIdx.x;            // nb * (T/PTT) blocks
    const int bl  = blk / (T_ / PTT);      // chunk-local batch index
    const int b   = b0 + bl;               // global batch index
    const int t0  = (blk % (T_ / PTT)) * PTT;
    const int tid = threadIdx.x;

    __shared__ float fr[PTT][MEL_];
    __shared__ float x1[PTT][PRE_];
    __shared__ float x2[PTT][E_];

    for (int i = tid; i < PTT * MEL_; i += 256) {
        int f = i / MEL_, m = i - f * MEL_;
        fr[f][m] = dec_input[((size_t)b * T_ + t0 + f) * MEL_ + m];
    }
    __syncthreads();

    // prenet1: row = tid (256 rows), K=80
    {
        float acc[PTT];
#pragma unroll
        for (int f = 0; f < PTT; ++f) acc[f] = pre_b1[tid];
        const float4* wr = reinterpret_cast<const float4*>(pre_w1 + tid * MEL_);
        for (int k4 = 0; k4 < MEL_ / 4; ++k4) {
            float4 w = wr[k4];
#pragma unroll
            for (int f = 0; f < PTT; ++f) {
                const float* fp = &fr[f][k4 * 4];
                acc[f] = fmaf(w.x, fp[0], fmaf(w.y, fp[1], fmaf(w.z, fp[2], fmaf(w.w, fp[3], acc[f]))));
            }
        }
#pragma unroll
        for (int f = 0; f < PTT; ++f) x1[f][tid] = fmaxf(acc[f], 0.f);
    }
    __syncthreads();

    // prenet2: row = tid (128 rows), K=256
    if (tid < E_) {
        float acc[PTT];
#pragma unroll
        for (int f = 0; f < PTT; ++f) acc[f] = pre_b2[tid];
        const float4* wr = reinterpret_cast<const float4*>(pre_w2 + tid * PRE_);
        for (int k4 = 0; k4 < PRE_ / 4; ++k4) {
            float4 w = wr[k4];
#pragma unroll
            for (int f = 0; f < PTT; ++f) {
                const float* fp = &x1[f][k4 * 4];
                acc[f] = fmaf(w.x, fp[0], fmaf(w.y, fp[1], fmaf(w.z, fp[2], fmaf(w.w, fp[3], acc[f]))));
            }
        }
#pragma unroll
        for (int f = 0; f < PTT; ++f) x2[f][tid] = fmaxf(acc[f], 0.f);
    }
    __syncthreads();

    // gi: 768 rows, K=128; bias folded in
    for (int r = tid; r < 3 * D_; r += 256) {
        float acc[PTT];
#pragma unroll
        for (int f = 0; f < PTT; ++f) acc[f] = attn_bih[r];
        const float4* wr = reinterpret_cast<const float4*>(attn_wih + r * E_);
        for (int k4 = 0; k4 < E_ / 4; ++k4) {
            float4 w = wr[k4];
#pragma unroll
            for (int f = 0; f < PTT; ++f) {
                const float* fp = &x2[f][k4 * 4];
                acc[f] = fmaf(w.x, fp[0], fmaf(w.y, fp[1], fmaf(w.z, fp[2], fmaf(w.w, fp[3], acc[f]))));
            }
        }
#pragma unroll
        for (int f = 0; f < PTT; ++f)
            gi_out[((size_t)bl * T_ + t0 + f) * (3 * D_) + r] = f2bf(acc[f]);
    }
}

// Persistent decoder: 1 block per batch element; enc[b] resident in LDS with
// XOR-swizzled 16B chunks (conflict-free ds_read_b128 in the score phase);
// packed bf16 weights L2-resident. The three gh GEMVs (whh @ prev-state) are
// merged into ONE phase at step start (4608 tasks). 15 barriers/step.
__global__ __launch_bounds__(TPB, 4) void decoder_persist(
    const float* __restrict__ enc_output,  // [B,L,D] fp32
    const ushort* __restrict__ attn_whh, const float* __restrict__ attn_bhh,
    const ushort* __restrict__ proj1_w, const float* __restrict__ proj1_b,
    const ushort* __restrict__ rnn1_wih, const ushort* __restrict__ rnn1_whh,
    const float* __restrict__ rnn1_bih, const float* __restrict__ rnn1_bhh,
    const ushort* __restrict__ rnn2_wih, const ushort* __restrict__ rnn2_whh,
    const float* __restrict__ rnn2_bih, const float* __restrict__ rnn2_bhh,
    const ushort* __restrict__ proj2_w, const float* __restrict__ proj2_b,
    const ushort* __restrict__ gi_g,       // chunk-local [nb,T,3*D] bf16
    int b0,
    float* __restrict__ mel_out,   // [B, T*RED, MEL]
    float* __restrict__ align_out) // [B, L, T]
{
    const int b    = blockIdx.x + b0;
    const int tid  = threadIdx.x;
    const int lane = tid & 63;
    const int wv   = tid >> 6;

    // LDS ~157 KB
    __shared__ __align__(16) ushort s_enc[L_ * ENC_C];   // 131072 B
    __shared__ __align__(16) float P[4608];              // partials (3 regions)
    __shared__ __align__(16) float P2b[640];             // proj2 partials
    __shared__ __align__(16) float s_ha[D_];
    __shared__ __align__(16) float s_h1[D_];
    __shared__ __align__(16) float s_h2[D_];
    __shared__ __align__(16) float s_dec[D_];
    __shared__ __align__(16) float s_y1[D_];
    __shared__ __align__(16) float s_y2[D_];
    __shared__ __align__(16) float s_ctx[D_];
    __shared__ __align__(16) float s_al[L_];
    __shared__ float s_pmax[4];
    __shared__ float s_psum[4];

    // ---- stage enc[b] fp32 -> bf16 LDS, XOR-swizzled ----
    // logical 16B chunk c of row r stored at slot (c&24) | ((c&7)^(r&7))
    {
        const float4* eb = reinterpret_cast<const float4*>(enc_output + (size_t)b * L_ * D_);
        for (int i = tid; i < (L_ * D_) / 4; i += TPB) {
            float4 f = eb[i];
            int row = i >> 6;        // 64 float4 (=8B out) per 256-elem row
            int c4  = i & 63;        // uint2 index within row
            int c    = c4 >> 1;      // 16B chunk 0..31
            int half = c4 & 1;
            int slot = (c & 24) | ((c & 7) ^ (row & 7));
            uint2 pk;
            pk.x = (unsigned)f2bf(f.x) | ((unsigned)f2bf(f.y) << 16);
            pk.y = (unsigned)f2bf(f.z) | ((unsigned)f2bf(f.w) << 16);
            *reinterpret_cast<uint2*>(s_enc + row * ENC_C + slot * 8 + half * 4) = pk;
        }
    }
    if (tid < D_) { s_ha[tid] = 0.f; s_h1[tid] = 0.f; s_h2[tid] = 0.f; }
    __syncthreads();

    // GRU combine from wih-partials gip (2-way) + gh-partials ghp (2-way)
    auto gru_combine = [&](const float* gip, const float* ghp,
                           const float* bih, const float* bhh,
                           float* h, const float* xin, float* y) {
        if (tid < D_) {
            int t0 = tid;
            float gir = gip[2 * t0] + gip[2 * t0 + 1] + bih[t0];
            float giz = gip[2 * (D_ + t0)] + gip[2 * (D_ + t0) + 1] + bih[D_ + t0];
            float gin = gip[2 * (2 * D_ + t0)] + gip[2 * (2 * D_ + t0) + 1] + bih[2 * D_ + t0];
            float ghr = ghp[2 * t0] + ghp[2 * t0 + 1] + bhh[t0];
            float ghz = ghp[2 * (D_ + t0)] + ghp[2 * (D_ + t0) + 1] + bhh[D_ + t0];
            float ghn = ghp[2 * (2 * D_ + t0)] + ghp[2 * (2 * D_ + t0) + 1] + bhh[2 * D_ + t0];
            float r = sigmoidf_(gir + ghr);
            float z = sigmoidf_(giz + ghz);
            float n = tanhf(gin + r * ghn);
            float hn = (1.f - z) * n + z * h[t0];
            h[t0] = hn;
            y[t0] = xin[t0] + hn;
        }
    };

    for (int t = 0; t < T_; ++t) {
        // [A] merged gh phase: whh @ {s_ha, s_h1, s_h2} (all prev-step state).
        // 4608 half-dot tasks (K=128). Regions: P[0..1536)=attn, [1536..3072)=rnn1,
        // [3072..4608)=rnn2.
        for (int task = tid; task < 4608; task += TPB) {
            const ushort* wP; const float* hv; int u;
            if (task < 1536)      { wP = attn_whh; hv = s_ha; u = task; }
            else if (task < 3072) { wP = rnn1_whh; hv = s_h1; u = task - 1536; }
            else                  { wP = rnn2_whh; hv = s_h2; u = task - 3072; }
            P[task] = dotpk<16>(wP, u, hv + (u & 1) * 128);
        }
        __syncthreads();

        // [B] attn GRU combine (gi from pre-pass)
        if (tid < D_) {
            const ushort* gp = gi_g + ((size_t)blockIdx.x * T_ + t) * (3 * D_);
            float gir = bfval(gp[tid]);
            float giz = bfval(gp[D_ + tid]);
            float gin = bfval(gp[2 * D_ + tid]);
            float ghr = P[2 * tid] + P[2 * tid + 1] + attn_bhh[tid];
            float ghz = P[2 * (D_ + tid)] + P[2 * (D_ + tid) + 1] + attn_bhh[D_ + tid];
            float ghn = P[2 * (2 * D_ + tid)] + P[2 * (2 * D_ + tid) + 1] + attn_bhh[2 * D_ + tid];
            float r = sigmoidf_(gir + ghr);
            float z = sigmoidf_(giz + ghz);
            float n = tanhf(gin + r * ghn);
            s_ha[tid] = (1.f - z) * n + z * s_ha[tid];
        }
        __syncthreads();

        // [C] scores: 256 rows x 4-way K-split; swizzled conflict-free b128 reads
        {
            int p = tid >> 8, l = tid & 255;
            const uint4* rowp = reinterpret_cast<const uint4*>(s_enc + l * ENC_C) + p * 8;
            const float* v = s_ha + p * 64;
            int rot = l & 7;
            float a0 = 0.f, a1 = 0.f, a2 = 0.f, a3 = 0.f;
#pragma unroll
            for (int k = 0; k < 8; k += 4) {
                uint4 u0 = rowp[(k + 0) ^ rot];
                uint4 u1 = rowp[(k + 1) ^ rot];
                uint4 u2 = rowp[(k + 2) ^ rot];
                uint4 u3 = rowp[(k + 3) ^ rot];
                a0 = acc8(u0, v + (k + 0) * 8, a0);
                a1 = acc8(u1, v + (k + 1) * 8, a1);
                a2 = acc8(u2, v + (k + 2) * 8, a2);
                a3 = acc8(u3, v + (k + 3) * 8, a3);
            }
            P[p * 256 + l] = (a0 + a1) + (a2 + a3);
        }
        __syncthreads();
        float sc = 0.f, e = 0.f;
        // [D] finalize score + block max
        if (tid < L_) {
            sc = P[tid] + P[256 + tid] + P[512 + tid] + P[768 + tid];
            float m = sc;
            for (int o = 32; o > 0; o >>= 1) m = fmaxf(m, __shfl_xor(m, o, 64));
            if (lane == 0) s_pmax[wv] = m;
        }
        __syncthreads();
        // [E] exp + block sum
        if (tid < L_) {
            float mm = fmaxf(fmaxf(s_pmax[0], s_pmax[1]), fmaxf(s_pmax[2], s_pmax[3]));
            e = expf(sc - mm);
            float sm = e;
            for (int o = 32; o > 0; o >>= 1) sm += __shfl_xor(sm, o, 64);
            if (lane == 0) s_psum[wv] = sm;
        }
        __syncthreads();
        // [F] alignment
        if (tid < L_) {
            float denom = s_psum[0] + s_psum[1] + s_psum[2] + s_psum[3];
            float al = e / denom;
            s_al[tid] = al;
            align_out[((size_t)b * L_ + tid) * T_ + t] = al;
        }
        __syncthreads();

        // [G] ctx partials: 256 cols x 4-way L-split (swizzle-aware scalar reads,
        // 2 lanes/bank = free)
        {
            int p = tid >> 8, d = tid & 255;
            int chigh = (d >> 3) & 24, clow = (d >> 3) & 7, el = d & 7;
            const float* alp = s_al + p * 64;
            float a0 = 0.f, a1 = 0.f;
            for (int l8 = 0; l8 < 8; ++l8) {
                const ushort* rb = s_enc + (p * 64 + l8 * 8) * ENC_C;
                const float* al8 = alp + l8 * 8;
#pragma unroll
                for (int dr = 0; dr < 8; ++dr) {
                    int slot = chigh | (clow ^ dr);
                    float vv = bfval(rb[dr * ENC_C + slot * 8 + el]);
                    if (dr & 1) a1 = fmaf(al8[dr], vv, a1);
                    else        a0 = fmaf(al8[dr], vv, a0);
                }
            }
            P[p * 256 + d] = a0 + a1;
        }
        __syncthreads();
        // [H] ctx combine
        if (tid < D_)
            s_ctx[tid] = P[tid] + P[256 + tid] + P[512 + tid] + P[768 + tid];
        __syncthreads();

        // [I] proj1 partials: 256 rows, K=512 split 4-way; cat = [ctx, ha] read
        // directly (no materialized concat)
        {
            int p = tid >> 8;
            const float* v = (p < 2) ? (s_ctx + p * 128) : (s_ha + (p - 2) * 128);
            P[tid] = dotpk<16>(proj1_w, tid, v);
        }
        __syncthreads();
        // [J] proj1 combine
        if (tid < D_)
            s_dec[tid] = P[tid] + P[256 + tid] + P[512 + tid] + P[768 + tid] + proj1_b[tid];
        __syncthreads();

        // [K] rnn1 wih gates (gh already in P[1536..3072))
        for (int task = tid; task < 1536; task += TPB)
            P[task] = dotpk<16>(rnn1_wih, task, s_dec + (task & 1) * 128);
        __syncthreads();
        gru_combine(P, P + 1536, rnn1_bih, rnn1_bhh, s_h1, s_dec, s_y1);
        __syncthreads();

        // [L] rnn2 wih gates (gh in P[3072..4608))
        for (int task = tid; task < 1536; task += TPB)
            P[task] = dotpk<16>(rnn2_wih, task, s_y1 + (task & 1) * 128);
        __syncthreads();
        gru_combine(P, P + 3072, rnn2_bih, rnn2_bhh, s_h2, s_y1, s_y2);
        __syncthreads();

        // [M] proj2 partials: 160 rows, K=256 split 4-way -> dedicated buffer
        if (tid < 640)
            P2b[tid] = dotpk<8>(proj2_w, tid, s_y2 + (tid & 3) * 64);
        __syncthreads();
        // [N] proj2 combine + mel store. No trailing barrier: next phase ([A] of
        // t+1) writes only P[] / reads s_ha,s_h1,s_h2 — all disjoint from P2b.
        if (tid < MEL_ * RED_) {
            float s = P2b[4 * tid] + P2b[4 * tid + 1] + P2b[4 * tid + 2] + P2b[4 * tid + 3] + proj2_b[tid];
            mel_out[(size_t)b * (T_ * RED_ * MEL_) + (size_t)t * (MEL_ * RED_) + tid] = s;
        }
    }
}

extern "C" void kernel_launch(void* const* d_in, const int* in_sizes, int n_in,
                              void* d_out, int out_size, void* d_ws, size_t ws_size,
                              hipStream_t stream) {
    const float* dec_input = (const float*)d_in[0];
    const float* enc_output= (const float*)d_in[1];
    const float* pre_w1    = (const float*)d_in[2];
    const float* pre_b1    = (const float*)d_in[3];
    const float* pre_w2    = (const float*)d_in[4];
    const float* pre_b2    = (const float*)d_in[5];
    const float* attn_wih  = (const float*)d_in[6];
    const float* attn_whh  = (const float*)d_in[7];
    const float* attn_bih  = (const float*)d_in[8];
    const float* attn_bhh  = (const float*)d_in[9];
    const float* proj1_w   = (const float*)d_in[10];
    const float* proj1_b   = (const float*)d_in[11];
    const float* rnn1_wih  = (const float*)d_in[12];
    const float* rnn1_whh  = (const float*)d_in[13];
    const float* rnn1_bih  = (const float*)d_in[14];
    const float* rnn1_bhh  = (const float*)d_in[15];
    const float* rnn2_wih  = (const float*)d_in[16];
    const float* rnn2_whh  = (const float*)d_in[17];
    const float* rnn2_bih  = (const float*)d_in[18];
    const float* rnn2_bhh  = (const float*)d_in[19];
    const float* proj2_w   = (const float*)d_in[20];
    const float* proj2_b   = (const float*)d_in[21];

    float* mel   = (float*)d_out;
    float* align = (float*)d_out + (size_t)B_ * T_ * RED_ * MEL_;

    // bf16 packed weight scratch (element counts)
    const int n_whh   = 3 * D_ * D_;        // 196608 (also rnn wih)
    const int n_proj1 = D_ * 2 * D_;        // 131072
    const int n_proj2 = MEL_ * RED_ * D_;   // 40960

    ushort* w = (ushort*)d_ws;
    ushort* c_attn_whh = w; w += n_whh;
    ushort* c_proj1    = w; w += n_proj1;
    ushort* c_rnn1_wih = w; w += n_whh;
    ushort* c_rnn1_whh = w; w += n_whh;
    ushort* c_rnn2_wih = w; w += n_whh;
    ushort* c_rnn2_whh = w; w += n_whh;
    ushort* c_proj2    = w; w += n_proj2;
    ushort* c_gi       = w;   // gi chunk buffer starts here

    // Wave-group-sequential pack (see pack_bf16_kernel for index math)
    auto pack = [&](const float* src, ushort* dst, int NT, int CH, int dA, int mA, int mB) {
        int n = NT * CH * 8;
        pack_bf16_kernel<<<dim3((n + 255) / 256), dim3(256), 0, stream>>>(
            src, dst, NT, CH, dA, mA, mB);
    };
    pack(attn_whh, c_attn_whh, 1536, 16, 2,   256, 128);  // row=t>>1, half=t&1
    pack(proj1_w,  c_proj1,    1024, 16, 256, 128, 512);  // row=t&255, p=t>>8
    pack(rnn1_wih, c_rnn1_wih, 1536, 16, 2,   256, 128);
    pack(rnn1_whh, c_rnn1_whh, 1536, 16, 2,   256, 128);
    pack(rnn2_wih, c_rnn2_wih, 1536, 16, 2,   256, 128);
    pack(rnn2_whh, c_rnn2_whh, 1536, 16, 2,   256, 128);
    pack(proj2_w,  c_proj2,    640,  8,  4,   256, 64);   // row=t>>2, p=t&3

    // gi chunking: fit as many batches as the workspace allows per pass
    // (observed harness ws >= 101 MB -> single pass of all 128).
    const size_t packed_elems = (size_t)(w - (ushort*)d_ws);
    const size_t gi_per_b = (size_t)T_ * 3 * D_;          // 384000 elems
    size_t avail = (ws_size / 2 > packed_elems) ? (ws_size / 2 - packed_elems) : 0;
    int bchunk = (int)(avail / gi_per_b);
    if (bchunk > B_) bchunk = B_;
    if (bchunk < 1)  bchunk = 1;   // last resort; needs ~3.1 MB total

    for (int b0 = 0; b0 < B_; b0 += bchunk) {
        int nb = (b0 + bchunk <= B_) ? bchunk : (B_ - b0);
        prenet_gi_kernel<<<dim3(nb * (T_ / PTT)), dim3(256), 0, stream>>>(
            dec_input, pre_w1, pre_b1, pre_w2, pre_b2, attn_wih, attn_bih,
            c_gi, b0);
        decoder_persist<<<dim3(nb), dim3(TPB), 0, stream>>>(
            enc_output,
            c_attn_whh, attn_bhh,
            c_proj1, proj1_b,
            c_rnn1_wih, c_rnn1_whh, rnn1_bih, rnn1_bhh,
            c_rnn2_wih, c_rnn2_whh, rnn2_bih, rnn2_bhh,
            c_proj2, proj2_b,
            c_gi, b0,
            mel, align);
    }
}